// Round 5
// baseline (854.101 us; speedup 1.0000x reference)
//
#include <hip/hip_runtime.h>
#include <stdint.h>

typedef __bf16 bf16x8 __attribute__((ext_vector_type(8)));
typedef float f32x4 __attribute__((ext_vector_type(4)));
typedef uint32_t u32x4 __attribute__((ext_vector_type(4)));

#define MFMA16(a,b,c) __builtin_amdgcn_mfma_f32_16x16x32_bf16(a,b,c,0,0,0)

// ---------------- workspace layout (bytes), total 151,552,000 ----------------
#define OFF_XB   0ull           // X bf16 [16384][256]              8,388,608
#define OFF_WT   8388608ull     // WqT/WkT/WvT bf16 [3][2048][256]  3,145,728
#define OFF_WTT  11534336ull    // Wq_tT/Wk_tT/Wv_tT same           3,145,728
#define OFF_WOT  14680064ull    // WoT bf16 [256][2048]             1,048,576
#define OFF_MB   15728640ull    // mish(t+r) bf16 [64][256]            32,768
#define OFF_BIAS 15761408ull    // bias fp32 [3][64][2048]          1,572,864
#define OFF_K    17334272ull    // K bf16 [512][256 l][256 d]      67,108,864
#define OFF_VT   84443136ull    // V^T bf16 [512][256 d][256 l]    67,108,864
#define WS_NEED  151552000ull

__device__ __forceinline__ uint16_t f2bf(float f) {
  uint32_t u = __builtin_bit_cast(uint32_t, f);
  return (uint16_t)((u + 0x7fffu + ((u >> 16) & 1u)) >> 16);
}
__device__ __forceinline__ bf16x8 ld16(const uint16_t* p) {
  u32x4 v = *(const u32x4*)p;
  return __builtin_bit_cast(bf16x8, v);
}
// per-wave 4KB bounce slab: [16 rows][128 bf16], row pitch 256B = 16 x 16B slots,
// slot XOR-swizzled by row&7 to break the 256B-stride bank pattern on b128 reads.
__device__ __forceinline__ void bounce_w2(char* slab, int row, int col, uint16_t val) {
  int slot = col >> 3;
  *(uint16_t*)(slab + row * 256 + (((slot ^ (row & 7)) & 15) << 4) + ((col & 7) << 1)) = val;
}
__device__ __forceinline__ bf16x8 bounce_r16(const char* slab, int row, int slot) {
  u32x4 v = *(const u32x4*)(slab + row * 256 + (((slot ^ (row & 7)) & 15) << 4));
  return __builtin_bit_cast(bf16x8, v);
}

// ---------------- ws-size sentinel + output init ----------------
__global__ void sentinel_kernel(float* out, float val) {
  out[blockIdx.x * 256 + threadIdx.x] = val;
}
__global__ void init_out(const float* bo, float* out) {
  int i = blockIdx.x * 256 + threadIdx.x;
  out[i] = bo[i & 255];
}

// ---------------- small prep kernels ----------------
__global__ void mish_kernel(const float* te, const float* re, uint16_t* mb) {
  int i = blockIdx.x * 256 + threadIdx.x;   // 64*256
  float x = te[i] + re[i];
  float sp = log1pf(__expf(x));
  mb[i] = f2bf(x * tanhf(sp));
}

__global__ void convx_kernel(const float* x, uint16_t* xb) {
  int i = blockIdx.x * 256 + threadIdx.x;   // 4096 blocks, 4 floats each
  float4 v = ((const float4*)x)[i];
  ushort4 o = make_ushort4(f2bf(v.x), f2bf(v.y), f2bf(v.z), f2bf(v.w));
  ((ushort4*)xb)[i] = o;
}

// transpose+convert 7 weight matrices to B^T (N x K) bf16 layouts
__global__ void wtrans_kernel(const float* w0, const float* w1, const float* w2,
                              const float* w3, const float* w4, const float* w5,
                              const float* w6, uint16_t* wt, uint16_t* wtt, uint16_t* wot) {
  int z = blockIdx.y;
  const float* src; uint16_t* dst; int C;
  if (z < 3)      { src = (z==0)?w0:((z==1)?w1:w2); dst = wt  + (size_t)z*524288;     C=2048; }
  else if (z < 6) { src = (z==3)?w3:((z==4)?w4:w5); dst = wtt + (size_t)(z-3)*524288; C=2048; }
  else            { src = w6; dst = wot;                                              C=256; }
  int R = (z < 6) ? 256 : 2048;
  __shared__ uint16_t tile[32][33];
  int tc = C >> 5;
  int bR = (blockIdx.x / tc) << 5, bC = (blockIdx.x % tc) << 5;
  int tx = threadIdx.x & 31, ty = threadIdx.x >> 5;  // 32 x 8
  #pragma unroll
  for (int i = 0; i < 4; i++) {
    int r = bR + ty + i * 8;
    tile[ty + i * 8][tx] = f2bf(src[(size_t)r * C + bC + tx]);
  }
  __syncthreads();
  #pragma unroll
  for (int i = 0; i < 4; i++) {
    int c = bC + ty + i * 8;
    dst[(size_t)c * R + bR + tx] = tile[tx][ty + i * 8];
  }
}

// ---------------- bias GEMM (no LDS): [3] x (m[64x256] @ Wt[256x2048] + b) -> fp32 ----------------
__global__ __launch_bounds__(256, 4)
void bias_gemm(const uint16_t* Mb, const uint16_t* WTT,
               const float* bq, const float* bk, const float* bv, float* biasAll) {
  int bid = blockIdx.x;            // 48 = 3 * 16
  int z = bid >> 4, nbt = bid & 15;
  int n0 = nbt << 7;
  const uint16_t* Bsrc = WTT + (size_t)z * 524288;
  const float* bvec = (z == 0) ? bq : ((z == 1) ? bk : bv);
  float* outp = biasAll + (size_t)z * 131072;
  int tid = threadIdx.x, lane = tid & 63, w = tid >> 6;
  int g = lane >> 4, ln = lane & 15;

  bf16x8 af[8];
  #pragma unroll
  for (int ks = 0; ks < 8; ks++)
    af[ks] = ld16(Mb + (size_t)(w*16 + ln) * 256 + ks*32 + g*8);
  f32x4 acc[8];
  #pragma unroll
  for (int j = 0; j < 8; j++) acc[j] = (f32x4){0.f,0.f,0.f,0.f};
  #pragma unroll
  for (int j = 0; j < 8; j++)
    #pragma unroll
    for (int ks = 0; ks < 8; ks++) {
      bf16x8 bf_ = ld16(Bsrc + (size_t)(n0 + j*16 + ln) * 256 + ks*32 + g*8);
      acc[j] = MFMA16(af[ks], bf_, acc[j]);
    }
  #pragma unroll
  for (int j = 0; j < 8; j++) {
    int colg = n0 + j*16 + ln;
    float bb = bvec[colg];
    #pragma unroll
    for (int r = 0; r < 4; r++)
      outp[(size_t)(w*16 + g*4 + r) * 2048 + colg] = acc[j][r] + bb;
  }
}

// ---------------- KV GEMM (no LDS): X[16384x256] @ W -> K (l,d) and V^T (d,l), bf16 ----------------
__global__ __launch_bounds__(256, 4)
void kv_gemm(const uint16_t* Xb, const uint16_t* WT, const float* biasAll,
             uint16_t* Kw, uint16_t* Vt) {
  int bid = blockIdx.x;               // 8192 = 2 * 256 * 16
  int z2 = bid >> 12, rem = bid & 4095;   // z2: 0=K, 1=V
  int mb = rem >> 4, nb = rem & 15;
  int m0 = mb << 6, n0 = nb << 7;     // 64-row x 128-col tile
  const uint16_t* Bsrc = WT + (size_t)(z2 + 1) * 524288;
  int bt = m0 >> 8;
  const float* bias = biasAll + (size_t)(z2 + 1) * 131072 + (size_t)bt * 2048;
  int tid = threadIdx.x, lane = tid & 63, w = tid >> 6;
  int g = lane >> 4, ln = lane & 15;

  bf16x8 af[8];
  #pragma unroll
  for (int ks = 0; ks < 8; ks++)
    af[ks] = ld16(Xb + (size_t)(m0 + w*16 + ln) * 256 + ks*32 + g*8);
  f32x4 acc[8];
  #pragma unroll
  for (int j = 0; j < 8; j++) acc[j] = (f32x4){0.f,0.f,0.f,0.f};
  #pragma unroll
  for (int j = 0; j < 8; j++)
    #pragma unroll
    for (int ks = 0; ks < 8; ks++) {
      bf16x8 bf_ = ld16(Bsrc + (size_t)(n0 + j*16 + ln) * 256 + ks*32 + g*8);
      acc[j] = MFMA16(af[ks], bf_, acc[j]);
    }
  #pragma unroll
  for (int j = 0; j < 8; j++) {
    int colg = n0 + j*16 + ln;
    int hh = colg >> 8, d = colg & 255;
    float bb = bias[colg];
    size_t hb = (size_t)(bt * 8 + hh) << 16;
    int l0 = (m0 & 255) + w*16 + g*4;
    if (z2 == 1) {   // V transposed: [d][l], 4 consecutive l per lane
      ushort4 pk = make_ushort4(f2bf(acc[j][0]+bb), f2bf(acc[j][1]+bb),
                                f2bf(acc[j][2]+bb), f2bf(acc[j][3]+bb));
      *(ushort4*)(Vt + hb + ((size_t)d << 8) + l0) = pk;
    } else {
      #pragma unroll
      for (int r = 0; r < 4; r++)
        Kw[hb + ((size_t)(l0 + r) << 8) + d] = f2bf(acc[j][r] + bb);
    }
  }
}

// ---------------- fused attention v3: per-wave 4KB slabs, 32KB LDS -> 3 blocks/CU ----------------
// block = (bt, h, qh); 1024 blocks; 8 waves x 16 q-rows = 128 q-rows/block.
// No __syncthreads: all LDS per-wave private; C/D->A bounces done in two 128-element halves.
__global__ __launch_bounds__(512, 4)
void attn_v3(const uint16_t* Xb, const uint16_t* WT, const float* Bi,
             const uint16_t* Kw, const uint16_t* Vt, const uint16_t* WoT,
             float* out) {
  __shared__ char smem[32768];
  int tid = threadIdx.x, lane = tid & 63, w = tid >> 6;
  int g = lane >> 4, ln = lane & 15;
  int bid = blockIdx.x;
  int bh = bid >> 1, qh = bid & 1;
  int bt = bh >> 3, h = bh & 7;
  const size_t kvbase = (size_t)bh << 16;
  int q0g = bt * 256 + qh * 128 + w * 16;   // first global q-row of this wave
  char* slab = smem + (w << 12);            // private 4KB = [16 rows][128 bf16] swz

  // ---- p0: Q = (X @ Wq[:,h] + bias_q) * (1/16); A,B fragments direct from global ----
  bf16x8 qx[8];
  #pragma unroll
  for (int ks = 0; ks < 8; ks++)
    qx[ks] = ld16(Xb + (size_t)(q0g + ln) * 256 + ks*32 + g*8);
  f32x4 qacc[16];
  #pragma unroll
  for (int f = 0; f < 16; f++) qacc[f] = (f32x4){0.f,0.f,0.f,0.f};
  #pragma unroll
  for (int f = 0; f < 16; f++)
    #pragma unroll
    for (int ks = 0; ks < 8; ks++) {
      bf16x8 wq = ld16(WT + (size_t)(h*256 + f*16 + ln) * 256 + ks*32 + g*8);
      qacc[f] = MFMA16(qx[ks], wq, qacc[f]);
    }
  #pragma unroll
  for (int f = 0; f < 16; f++) {
    float bb = Bi[bt*2048 + h*256 + f*16 + ln];
    #pragma unroll
    for (int r = 0; r < 4; r++) qacc[f][r] = (qacc[f][r] + bb) * 0.0625f;
  }
  // Q bounce in two d-halves through the 4KB slab:
  // C/D (q=g*4+r, d=f*16+ln) -> slab[q][d-half] -> A-frags (m=ln, k=d contiguous)
  bf16x8 qa[8];
  #pragma unroll
  for (int dh = 0; dh < 2; dh++) {
    #pragma unroll
    for (int f2 = 0; f2 < 8; f2++) {
      int f = dh*8 + f2;
      #pragma unroll
      for (int r = 0; r < 4; r++)
        bounce_w2(slab, g*4 + r, f2*16 + ln, f2bf(qacc[f][r]));
    }
    #pragma unroll
    for (int ks2 = 0; ks2 < 4; ks2++)
      qa[dh*4 + ks2] = bounce_r16(slab, ln, ks2*4 + g);
  }

  // ---- p1: S = Q K^T; K fragments direct from global ----
  f32x4 S[16];
  #pragma unroll
  for (int f = 0; f < 16; f++) S[f] = (f32x4){0.f,0.f,0.f,0.f};
  #pragma unroll
  for (int f = 0; f < 16; f++)
    #pragma unroll
    for (int ks = 0; ks < 8; ks++) {
      bf16x8 bk = ld16(Kw + kvbase + (size_t)(f*16 + ln) * 256 + ks*32 + g*8);
      S[f] = MFMA16(qa[ks], bk, S[f]);
    }

  // ---- p2: row softmax (q=g*4+r; k spread over f and the 16 ln-lanes of group g) ----
  #pragma unroll
  for (int r = 0; r < 4; r++) {
    float mx = -3.4e38f;
    #pragma unroll
    for (int f = 0; f < 16; f++) mx = fmaxf(mx, S[f][r]);
    #pragma unroll
    for (int m_ = 1; m_ < 16; m_ <<= 1) mx = fmaxf(mx, __shfl_xor(mx, m_, 64));
    float sum = 0.f;
    #pragma unroll
    for (int f = 0; f < 16; f++) {
      float p = __expf(S[f][r] - mx);
      S[f][r] = p; sum += p;
    }
    #pragma unroll
    for (int m_ = 1; m_ < 16; m_ <<= 1) sum += __shfl_xor(sum, m_, 64);
    float inv = 1.f / sum;
    #pragma unroll
    for (int f = 0; f < 16; f++) S[f][r] *= inv;
  }

  // ---- p3: P bounce (two k-halves) -> B-frags; O^T = V^T P^T, V^T direct from global ----
  bf16x8 pb[8];
  #pragma unroll
  for (int kh = 0; kh < 2; kh++) {
    #pragma unroll
    for (int f2 = 0; f2 < 8; f2++) {
      int f = kh*8 + f2;
      #pragma unroll
      for (int r = 0; r < 4; r++)
        bounce_w2(slab, g*4 + r, f2*16 + ln, f2bf(S[f][r]));
    }
    #pragma unroll
    for (int ks2 = 0; ks2 < 4; ks2++)
      pb[kh*4 + ks2] = bounce_r16(slab, ln, ks2*4 + g);
  }

  f32x4 O[16];
  #pragma unroll
  for (int df = 0; df < 16; df++) O[df] = (f32x4){0.f,0.f,0.f,0.f};
  #pragma unroll
  for (int df = 0; df < 16; df++)
    #pragma unroll
    for (int ks = 0; ks < 8; ks++) {
      bf16x8 vv = ld16(Vt + kvbase + (size_t)(df*16 + ln) * 256 + ks*32 + g*8);
      O[df] = MFMA16(vv, pb[ks], O[df]);   // D[m=d][n=q]
    }

  // ---- p4: O bounce (two d-halves): (d=df*16+g*4+r, q=ln) -> slab[q][d-half] -> A-frags ----
  bf16x8 oa[8];
  #pragma unroll
  for (int dh = 0; dh < 2; dh++) {
    #pragma unroll
    for (int df2 = 0; df2 < 8; df2++) {
      int df = dh*8 + df2;
      #pragma unroll
      for (int r = 0; r < 4; r++)
        bounce_w2(slab, ln, df2*16 + g*4 + r, f2bf(O[df][r]));
    }
    #pragma unroll
    for (int ks2 = 0; ks2 < 4; ks2++)
      oa[dh*4 + ks2] = bounce_r16(slab, ln, ks2*4 + g);
  }

  // ---- p5: out[q][e] += O[q][:] @ Wo[h*256:(h+1)*256][e]; Wo fragments direct ----
  f32x4 oacc[16];
  #pragma unroll
  for (int ef = 0; ef < 16; ef++) oacc[ef] = (f32x4){0.f,0.f,0.f,0.f};
  #pragma unroll
  for (int ef = 0; ef < 16; ef++)
    #pragma unroll
    for (int ks = 0; ks < 8; ks++) {
      bf16x8 wb = ld16(WoT + (size_t)(ef*16 + ln) * 2048 + h*256 + ks*32 + g*8);
      oacc[ef] = MFMA16(oa[ks], wb, oacc[ef]);
    }
  #pragma unroll
  for (int ef = 0; ef < 16; ef++)
    #pragma unroll
    for (int r = 0; r < 4; r++)
      atomicAdd(out + (size_t)(q0g + g*4 + r) * 256 + ef*16 + ln, oacc[ef][r]);
}

// ---------------- launcher ----------------
extern "C" void kernel_launch(void* const* d_in, const int* in_sizes, int n_in,
                              void* d_out, int out_size, void* d_ws, size_t ws_size,
                              hipStream_t stream) {
  float* out = (float*)d_out;
  if (ws_size < WS_NEED) {
    sentinel_kernel<<<16384, 256, 0, stream>>>(out, 1000.0f + (float)(ws_size >> 20));
    return;
  }
  const float* x   = (const float*)d_in[0];
  const float* te  = (const float*)d_in[1];
  const float* re  = (const float*)d_in[2];
  const float* Wq  = (const float*)d_in[3];
  const float* Wk  = (const float*)d_in[4];
  const float* Wv  = (const float*)d_in[5];
  const float* Wqt = (const float*)d_in[6];
  const float* bqt = (const float*)d_in[7];
  const float* Wkt = (const float*)d_in[8];
  const float* bkt = (const float*)d_in[9];
  const float* Wvt = (const float*)d_in[10];
  const float* bvt = (const float*)d_in[11];
  const float* Wo  = (const float*)d_in[12];
  const float* bo  = (const float*)d_in[13];
  char* ws = (char*)d_ws;
  uint16_t* Xb  = (uint16_t*)(ws + OFF_XB);
  uint16_t* WT  = (uint16_t*)(ws + OFF_WT);
  uint16_t* WTT = (uint16_t*)(ws + OFF_WTT);
  uint16_t* WoT = (uint16_t*)(ws + OFF_WOT);
  uint16_t* Mb  = (uint16_t*)(ws + OFF_MB);
  float*    Bi  = (float*)(ws + OFF_BIAS);
  uint16_t* Kw  = (uint16_t*)(ws + OFF_K);
  uint16_t* Vt  = (uint16_t*)(ws + OFF_VT);

  mish_kernel<<<64, 256, 0, stream>>>(te, re, Mb);
  wtrans_kernel<<<dim3(512, 7), 256, 0, stream>>>(Wq, Wk, Wv, Wqt, Wkt, Wvt, Wo, WT, WTT, WoT);
  convx_kernel<<<4096, 256, 0, stream>>>(x, Xb);
  bias_gemm<<<48, 256, 0, stream>>>(Mb, WTT, bqt, bkt, bvt, Bi);
  kv_gemm<<<8192, 256, 0, stream>>>(Xb, WT, Bi, Kw, Vt);
  init_out<<<16384, 256, 0, stream>>>(bo, out);
  attn_v3<<<1024, 512, 0, stream>>>(Xb, WT, Bi, Kw, Vt, WoT, out);
}

// Round 6
// 507.097 us; speedup vs baseline: 1.6843x; 1.6843x over previous
//
#include <hip/hip_runtime.h>
#include <stdint.h>

typedef __bf16 bf16x8 __attribute__((ext_vector_type(8)));
typedef float f32x4 __attribute__((ext_vector_type(4)));
typedef uint32_t u32x4 __attribute__((ext_vector_type(4)));

#define MFMA16(a,b,c) __builtin_amdgcn_mfma_f32_16x16x32_bf16(a,b,c,0,0,0)

// ---------------- workspace layout (bytes), total 151,552,000 ----------------
#define OFF_XB   0ull           // X bf16 [16384][256]              8,388,608
#define OFF_WT   8388608ull     // WqT/WkT/WvT bf16 [3][2048][256]  3,145,728
#define OFF_WTT  11534336ull    // Wq_tT/Wk_tT/Wv_tT same           3,145,728
#define OFF_WOT  14680064ull    // WoT bf16 [256][2048]             1,048,576
#define OFF_MB   15728640ull    // mish(t+r) bf16 [64][256]            32,768
#define OFF_BIAS 15761408ull    // bias fp32 [3][64][2048]          1,572,864
#define OFF_K    17334272ull    // K bf16 [512][256 l][256 d]      67,108,864
#define OFF_VT   84443136ull    // V^T bf16 [512][256 d][256 l]    67,108,864
#define WS_NEED  151552000ull

__device__ __forceinline__ uint16_t f2bf(float f) {
  uint32_t u = __builtin_bit_cast(uint32_t, f);
  return (uint16_t)((u + 0x7fffu + ((u >> 16) & 1u)) >> 16);
}
__device__ __forceinline__ bf16x8 ld16(const uint16_t* p) {
  u32x4 v = *(const u32x4*)p;
  return __builtin_bit_cast(bf16x8, v);
}
// per-wave 4KB bounce slab: [16 rows][128 bf16], row pitch 256B = 16 x 16B slots,
// slot XOR-swizzled by row&7 to break the 256B-stride bank pattern on b128 reads.
__device__ __forceinline__ void bounce_w2(char* slab, int row, int col, uint16_t val) {
  int slot = col >> 3;
  *(uint16_t*)(slab + row * 256 + (((slot ^ (row & 7)) & 15) << 4) + ((col & 7) << 1)) = val;
}
__device__ __forceinline__ bf16x8 bounce_r16(const char* slab, int row, int slot) {
  u32x4 v = *(const u32x4*)(slab + row * 256 + (((slot ^ (row & 7)) & 15) << 4));
  return __builtin_bit_cast(bf16x8, v);
}

// ---------------- ws-size sentinel + output init ----------------
__global__ void sentinel_kernel(float* out, float val) {
  out[blockIdx.x * 256 + threadIdx.x] = val;
}
__global__ void init_out(const float* bo, float* out) {
  int i = blockIdx.x * 256 + threadIdx.x;
  out[i] = bo[i & 255];
}

// ---------------- small prep kernels ----------------
__global__ void mish_kernel(const float* te, const float* re, uint16_t* mb) {
  int i = blockIdx.x * 256 + threadIdx.x;   // 64*256
  float x = te[i] + re[i];
  float sp = log1pf(__expf(x));
  mb[i] = f2bf(x * tanhf(sp));
}

__global__ void convx_kernel(const float* x, uint16_t* xb) {
  int i = blockIdx.x * 256 + threadIdx.x;   // 4096 blocks, 4 floats each
  float4 v = ((const float4*)x)[i];
  ushort4 o = make_ushort4(f2bf(v.x), f2bf(v.y), f2bf(v.z), f2bf(v.w));
  ((ushort4*)xb)[i] = o;
}

// transpose+convert 7 weight matrices to B^T (N x K) bf16 layouts
__global__ void wtrans_kernel(const float* w0, const float* w1, const float* w2,
                              const float* w3, const float* w4, const float* w5,
                              const float* w6, uint16_t* wt, uint16_t* wtt, uint16_t* wot) {
  int z = blockIdx.y;
  const float* src; uint16_t* dst; int C;
  if (z < 3)      { src = (z==0)?w0:((z==1)?w1:w2); dst = wt  + (size_t)z*524288;     C=2048; }
  else if (z < 6) { src = (z==3)?w3:((z==4)?w4:w5); dst = wtt + (size_t)(z-3)*524288; C=2048; }
  else            { src = w6; dst = wot;                                              C=256; }
  int R = (z < 6) ? 256 : 2048;
  __shared__ uint16_t tile[32][33];
  int tc = C >> 5;
  int bR = (blockIdx.x / tc) << 5, bC = (blockIdx.x % tc) << 5;
  int tx = threadIdx.x & 31, ty = threadIdx.x >> 5;  // 32 x 8
  #pragma unroll
  for (int i = 0; i < 4; i++) {
    int r = bR + ty + i * 8;
    tile[ty + i * 8][tx] = f2bf(src[(size_t)r * C + bC + tx]);
  }
  __syncthreads();
  #pragma unroll
  for (int i = 0; i < 4; i++) {
    int c = bC + ty + i * 8;
    dst[(size_t)c * R + bR + tx] = tile[tx][ty + i * 8];
  }
}

// ---------------- bias GEMM (no LDS): [3] x (m[64x256] @ Wt[256x2048] + b) -> fp32 ----------------
__global__ __launch_bounds__(256, 4)
void bias_gemm(const uint16_t* Mb, const uint16_t* WTT,
               const float* bq, const float* bk, const float* bv, float* biasAll) {
  int bid = blockIdx.x;            // 48 = 3 * 16
  int z = bid >> 4, nbt = bid & 15;
  int n0 = nbt << 7;
  const uint16_t* Bsrc = WTT + (size_t)z * 524288;
  const float* bvec = (z == 0) ? bq : ((z == 1) ? bk : bv);
  float* outp = biasAll + (size_t)z * 131072;
  int tid = threadIdx.x, lane = tid & 63, w = tid >> 6;
  int g = lane >> 4, ln = lane & 15;

  bf16x8 af[8];
  #pragma unroll
  for (int ks = 0; ks < 8; ks++)
    af[ks] = ld16(Mb + (size_t)(w*16 + ln) * 256 + ks*32 + g*8);
  f32x4 acc[8];
  #pragma unroll
  for (int j = 0; j < 8; j++) acc[j] = (f32x4){0.f,0.f,0.f,0.f};
  #pragma unroll
  for (int j = 0; j < 8; j++)
    #pragma unroll
    for (int ks = 0; ks < 8; ks++) {
      bf16x8 bf_ = ld16(Bsrc + (size_t)(n0 + j*16 + ln) * 256 + ks*32 + g*8);
      acc[j] = MFMA16(af[ks], bf_, acc[j]);
    }
  #pragma unroll
  for (int j = 0; j < 8; j++) {
    int colg = n0 + j*16 + ln;
    float bb = bvec[colg];
    #pragma unroll
    for (int r = 0; r < 4; r++)
      outp[(size_t)(w*16 + g*4 + r) * 2048 + colg] = acc[j][r] + bb;
  }
}

// ---------------- KV GEMM (no LDS): X[16384x256] @ W -> K (l,d) and V^T (d,l), bf16 ----------------
__global__ __launch_bounds__(256, 4)
void kv_gemm(const uint16_t* Xb, const uint16_t* WT, const float* biasAll,
             uint16_t* Kw, uint16_t* Vt) {
  int bid = blockIdx.x;               // 8192 = 2 * 256 * 16
  int z2 = bid >> 12, rem = bid & 4095;   // z2: 0=K, 1=V
  int mb = rem >> 4, nb = rem & 15;
  int m0 = mb << 6, n0 = nb << 7;     // 64-row x 128-col tile
  const uint16_t* Bsrc = WT + (size_t)(z2 + 1) * 524288;
  int bt = m0 >> 8;
  const float* bias = biasAll + (size_t)(z2 + 1) * 131072 + (size_t)bt * 2048;
  int tid = threadIdx.x, lane = tid & 63, w = tid >> 6;
  int g = lane >> 4, ln = lane & 15;

  bf16x8 af[8];
  #pragma unroll
  for (int ks = 0; ks < 8; ks++)
    af[ks] = ld16(Xb + (size_t)(m0 + w*16 + ln) * 256 + ks*32 + g*8);
  f32x4 acc[8];
  #pragma unroll
  for (int j = 0; j < 8; j++) acc[j] = (f32x4){0.f,0.f,0.f,0.f};
  #pragma unroll
  for (int j = 0; j < 8; j++)
    #pragma unroll
    for (int ks = 0; ks < 8; ks++) {
      bf16x8 bf_ = ld16(Bsrc + (size_t)(n0 + j*16 + ln) * 256 + ks*32 + g*8);
      acc[j] = MFMA16(af[ks], bf_, acc[j]);
    }
  #pragma unroll
  for (int j = 0; j < 8; j++) {
    int colg = n0 + j*16 + ln;
    int hh = colg >> 8, d = colg & 255;
    float bb = bias[colg];
    size_t hb = (size_t)(bt * 8 + hh) << 16;
    int l0 = (m0 & 255) + w*16 + g*4;
    if (z2 == 1) {   // V transposed: [d][l], 4 consecutive l per lane
      ushort4 pk = make_ushort4(f2bf(acc[j][0]+bb), f2bf(acc[j][1]+bb),
                                f2bf(acc[j][2]+bb), f2bf(acc[j][3]+bb));
      *(ushort4*)(Vt + hb + ((size_t)d << 8) + l0) = pk;
    } else {
      #pragma unroll
      for (int r = 0; r < 4; r++)
        Kw[hb + ((size_t)(l0 + r) << 8) + d] = f2bf(acc[j][r] + bb);
    }
  }
}

// ---------------- fused attention v4: v3 + shared LDS staging of the 4 operand streams ----------------
// block = (bt, h, qh); 1024 blocks; 8 waves x 16 q-rows.
// LDS: [0,32KB) shared stage buffer [64 rows][256 bf16] swz (sync-guarded);
//      [32KB,64KB) 8 x 4KB per-wave bounce slabs (wave-private, unchanged from v3).
__global__ __launch_bounds__(512, 2)
void attn_v4(const uint16_t* Xb, const uint16_t* WT, const float* Bi,
             const uint16_t* Kw, const uint16_t* Vt, const uint16_t* WoT,
             float* out) {
  __shared__ char smem[65536];
  int tid = threadIdx.x, lane = tid & 63, w = tid >> 6;
  int g = lane >> 4, ln = lane & 15;
  int bid = blockIdx.x;
  int bh = bid >> 1, qh = bid & 1;
  int bt = bh >> 3, h = bh & 7;
  const size_t kvbase = (size_t)bh << 16;
  int q0g = bt * 256 + qh * 128 + w * 16;   // first global q-row of this wave
  char* stage = smem;                        // shared [64][256]bf16, pitch 512B, 32 slots
  char* slab  = smem + 32768 + (w << 12);    // private 4KB

  // stage one [64 rows][256 cols] bf16 tile; rowstride in elements
  auto stage_tile = [&](const uint16_t* src, int rowstride) {
    #pragma unroll
    for (int it = 0; it < 4; it++) {
      int c = tid + (it << 9);
      int row = c >> 5, sl = c & 31;
      u32x4 v = *(const u32x4*)(src + (size_t)row * rowstride + sl * 8);
      *(u32x4*)(stage + row * 512 + ((sl ^ (row & 7)) << 4)) = v;
    }
  };
  auto frag = [&](int row, int slot) -> bf16x8 {
    u32x4 v = *(const u32x4*)(stage + row * 512 + ((slot ^ (row & 7)) << 4));
    return __builtin_bit_cast(bf16x8, v);
  };

  // ---- p0: Q = (X @ Wq[:,h] + bias_q) * (1/16); WqT tiles staged in LDS ----
  bf16x8 qx[8];
  #pragma unroll
  for (int ks = 0; ks < 8; ks++)
    qx[ks] = ld16(Xb + (size_t)(q0g + ln) * 256 + ks*32 + g*8);
  f32x4 qacc[16];
  #pragma unroll
  for (int f = 0; f < 16; f++) qacc[f] = (f32x4){0.f,0.f,0.f,0.f};
  #pragma unroll
  for (int t = 0; t < 4; t++) {
    __syncthreads();
    stage_tile(WT + (size_t)(h*256 + t*64) * 256, 256);
    __syncthreads();
    #pragma unroll
    for (int ks = 0; ks < 8; ks++)
      #pragma unroll
      for (int f2 = 0; f2 < 4; f2++)
        qacc[t*4+f2] = MFMA16(qx[ks], frag(f2*16 + ln, ks*4 + g), qacc[t*4+f2]);
  }
  #pragma unroll
  for (int f = 0; f < 16; f++) {
    float bb = Bi[bt*2048 + h*256 + f*16 + ln];
    #pragma unroll
    for (int r = 0; r < 4; r++) qacc[f][r] = (qacc[f][r] + bb) * 0.0625f;
  }
  // Q bounce (per-wave slab, unchanged from v3)
  bf16x8 qa[8];
  #pragma unroll
  for (int dh = 0; dh < 2; dh++) {
    #pragma unroll
    for (int f2 = 0; f2 < 8; f2++) {
      int f = dh*8 + f2;
      #pragma unroll
      for (int r = 0; r < 4; r++)
        bounce_w2(slab, g*4 + r, f2*16 + ln, f2bf(qacc[f][r]));
    }
    #pragma unroll
    for (int ks2 = 0; ks2 < 4; ks2++)
      qa[dh*4 + ks2] = bounce_r16(slab, ln, ks2*4 + g);
  }

  // ---- p1: S = Q K^T; K tiles staged in LDS ----
  f32x4 S[16];
  #pragma unroll
  for (int f = 0; f < 16; f++) S[f] = (f32x4){0.f,0.f,0.f,0.f};
  #pragma unroll
  for (int t = 0; t < 4; t++) {
    __syncthreads();
    stage_tile(Kw + kvbase + (size_t)(t*64) * 256, 256);
    __syncthreads();
    #pragma unroll
    for (int ks = 0; ks < 8; ks++)
      #pragma unroll
      for (int f2 = 0; f2 < 4; f2++)
        S[t*4+f2] = MFMA16(qa[ks], frag(f2*16 + ln, ks*4 + g), S[t*4+f2]);
  }

  // ---- p2: row softmax (unchanged) ----
  #pragma unroll
  for (int r = 0; r < 4; r++) {
    float mx = -3.4e38f;
    #pragma unroll
    for (int f = 0; f < 16; f++) mx = fmaxf(mx, S[f][r]);
    #pragma unroll
    for (int m_ = 1; m_ < 16; m_ <<= 1) mx = fmaxf(mx, __shfl_xor(mx, m_, 64));
    float sum = 0.f;
    #pragma unroll
    for (int f = 0; f < 16; f++) {
      float p = __expf(S[f][r] - mx);
      S[f][r] = p; sum += p;
    }
    #pragma unroll
    for (int m_ = 1; m_ < 16; m_ <<= 1) sum += __shfl_xor(sum, m_, 64);
    float inv = 1.f / sum;
    #pragma unroll
    for (int f = 0; f < 16; f++) S[f][r] *= inv;
  }

  // ---- p3: P bounce (per-wave slab, unchanged); O^T = V^T P^T with V^T tiles staged ----
  bf16x8 pb[8];
  #pragma unroll
  for (int kh = 0; kh < 2; kh++) {
    #pragma unroll
    for (int f2 = 0; f2 < 8; f2++) {
      int f = kh*8 + f2;
      #pragma unroll
      for (int r = 0; r < 4; r++)
        bounce_w2(slab, g*4 + r, f2*16 + ln, f2bf(S[f][r]));
    }
    #pragma unroll
    for (int ks2 = 0; ks2 < 4; ks2++)
      pb[kh*4 + ks2] = bounce_r16(slab, ln, ks2*4 + g);
  }

  f32x4 O[16];
  #pragma unroll
  for (int df = 0; df < 16; df++) O[df] = (f32x4){0.f,0.f,0.f,0.f};
  #pragma unroll
  for (int t = 0; t < 4; t++) {
    __syncthreads();
    stage_tile(Vt + kvbase + (size_t)(t*64) * 256, 256);
    __syncthreads();
    #pragma unroll
    for (int ks = 0; ks < 8; ks++)
      #pragma unroll
      for (int df2 = 0; df2 < 4; df2++)
        O[t*4+df2] = MFMA16(frag(df2*16 + ln, ks*4 + g), pb[ks], O[t*4+df2]);  // D[m=d][n=q]
  }

  // ---- p4: O bounce (per-wave slab, unchanged) ----
  bf16x8 oa[8];
  #pragma unroll
  for (int dh = 0; dh < 2; dh++) {
    #pragma unroll
    for (int df2 = 0; df2 < 8; df2++) {
      int df = dh*8 + df2;
      #pragma unroll
      for (int r = 0; r < 4; r++)
        bounce_w2(slab, ln, df2*16 + g*4 + r, f2bf(O[df][r]));
    }
    #pragma unroll
    for (int ks2 = 0; ks2 < 4; ks2++)
      oa[dh*4 + ks2] = bounce_r16(slab, ln, ks2*4 + g);
  }

  // ---- p5: out += O @ Wo[h*256:(h+1)*256]; WoT tiles staged in LDS ----
  f32x4 oacc[16];
  #pragma unroll
  for (int ef = 0; ef < 16; ef++) oacc[ef] = (f32x4){0.f,0.f,0.f,0.f};
  #pragma unroll
  for (int t = 0; t < 4; t++) {
    __syncthreads();
    stage_tile(WoT + (size_t)(t*64) * 2048 + h*256, 2048);
    __syncthreads();
    #pragma unroll
    for (int ks = 0; ks < 8; ks++)
      #pragma unroll
      for (int ef2 = 0; ef2 < 4; ef2++)
        oacc[t*4+ef2] = MFMA16(oa[ks], frag(ef2*16 + ln, ks*4 + g), oacc[t*4+ef2]);
  }
  #pragma unroll
  for (int ef = 0; ef < 16; ef++)
    #pragma unroll
    for (int r = 0; r < 4; r++)
      atomicAdd(out + (size_t)(q0g + g*4 + r) * 256 + ef*16 + ln, oacc[ef][r]);
}

// ---------------- launcher ----------------
extern "C" void kernel_launch(void* const* d_in, const int* in_sizes, int n_in,
                              void* d_out, int out_size, void* d_ws, size_t ws_size,
                              hipStream_t stream) {
  float* out = (float*)d_out;
  if (ws_size < WS_NEED) {
    sentinel_kernel<<<16384, 256, 0, stream>>>(out, 1000.0f + (float)(ws_size >> 20));
    return;
  }
  const float* x   = (const float*)d_in[0];
  const float* te  = (const float*)d_in[1];
  const float* re  = (const float*)d_in[2];
  const float* Wq  = (const float*)d_in[3];
  const float* Wk  = (const float*)d_in[4];
  const float* Wv  = (const float*)d_in[5];
  const float* Wqt = (const float*)d_in[6];
  const float* bqt = (const float*)d_in[7];
  const float* Wkt = (const float*)d_in[8];
  const float* bkt = (const float*)d_in[9];
  const float* Wvt = (const float*)d_in[10];
  const float* bvt = (const float*)d_in[11];
  const float* Wo  = (const float*)d_in[12];
  const float* bo  = (const float*)d_in[13];
  char* ws = (char*)d_ws;
  uint16_t* Xb  = (uint16_t*)(ws + OFF_XB);
  uint16_t* WT  = (uint16_t*)(ws + OFF_WT);
  uint16_t* WTT = (uint16_t*)(ws + OFF_WTT);
  uint16_t* WoT = (uint16_t*)(ws + OFF_WOT);
  uint16_t* Mb  = (uint16_t*)(ws + OFF_MB);
  float*    Bi  = (float*)(ws + OFF_BIAS);
  uint16_t* Kw  = (uint16_t*)(ws + OFF_K);
  uint16_t* Vt  = (uint16_t*)(ws + OFF_VT);

  mish_kernel<<<64, 256, 0, stream>>>(te, re, Mb);
  wtrans_kernel<<<dim3(512, 7), 256, 0, stream>>>(Wq, Wk, Wv, Wqt, Wkt, Wvt, Wo, WT, WTT, WoT);
  convx_kernel<<<4096, 256, 0, stream>>>(x, Xb);
  bias_gemm<<<48, 256, 0, stream>>>(Mb, WTT, bqt, bkt, bvt, Bi);
  kv_gemm<<<8192, 256, 0, stream>>>(Xb, WT, Bi, Kw, Vt);
  init_out<<<16384, 256, 0, stream>>>(bo, out);
  attn_v4<<<1024, 512, 0, stream>>>(Xb, WT, Bi, Kw, Vt, WoT, out);
}

// Round 7
// 324.242 us; speedup vs baseline: 2.6342x; 1.5639x over previous
//
#include <hip/hip_runtime.h>
#include <stdint.h>

typedef __bf16 bf16x8 __attribute__((ext_vector_type(8)));
typedef float f32x4 __attribute__((ext_vector_type(4)));
typedef uint32_t u32x4 __attribute__((ext_vector_type(4)));

#define MFMA16(a,b,c) __builtin_amdgcn_mfma_f32_16x16x32_bf16(a,b,c,0,0,0)

// ---------------- workspace layout (bytes), total 151,552,000 ----------------
#define OFF_XB   0ull           // X bf16 [16384][256]              8,388,608
#define OFF_WT   8388608ull     // WqT/WkT/WvT bf16 [3][2048][256]  3,145,728
#define OFF_WTT  11534336ull    // Wq_tT/Wk_tT/Wv_tT same           3,145,728
#define OFF_WOT  14680064ull    // WoT bf16 [256][2048]             1,048,576
#define OFF_MB   15728640ull    // mish(t+r) bf16 [64][256]            32,768
#define OFF_BIAS 15761408ull    // bias fp32 [3][64][2048]          1,572,864
#define OFF_K    17334272ull    // K bf16 [512][256 l][256 d]      67,108,864
#define OFF_VT   84443136ull    // V^T bf16 [512][256 d][256 l]    67,108,864
#define WS_NEED  151552000ull

__device__ __forceinline__ uint16_t f2bf(float f) {
  uint32_t u = __builtin_bit_cast(uint32_t, f);
  return (uint16_t)((u + 0x7fffu + ((u >> 16) & 1u)) >> 16);
}
__device__ __forceinline__ bf16x8 ld16(const uint16_t* p) {
  u32x4 v = *(const u32x4*)p;
  return __builtin_bit_cast(bf16x8, v);
}
// per-wave 4KB bounce slab: [16 rows][128 bf16], row pitch 256B = 16 x 16B slots,
// slot XOR-swizzled by row&7 to break the 256B-stride bank pattern on b128 reads.
__device__ __forceinline__ void bounce_w2(char* slab, int row, int col, uint16_t val) {
  int slot = col >> 3;
  *(uint16_t*)(slab + row * 256 + (((slot ^ (row & 7)) & 15) << 4) + ((col & 7) << 1)) = val;
}
__device__ __forceinline__ bf16x8 bounce_r16(const char* slab, int row, int slot) {
  u32x4 v = *(const u32x4*)(slab + row * 256 + (((slot ^ (row & 7)) & 15) << 4));
  return __builtin_bit_cast(bf16x8, v);
}

// ---------------- ws-size sentinel + output init ----------------
__global__ void sentinel_kernel(float* out, float val) {
  out[blockIdx.x * 256 + threadIdx.x] = val;
}
__global__ void init_out(const float* bo, float* out) {
  int i = blockIdx.x * 256 + threadIdx.x;
  out[i] = bo[i & 255];
}

// ---------------- small prep kernels ----------------
__global__ void mish_kernel(const float* te, const float* re, uint16_t* mb) {
  int i = blockIdx.x * 256 + threadIdx.x;   // 64*256
  float x = te[i] + re[i];
  float sp = log1pf(__expf(x));
  mb[i] = f2bf(x * tanhf(sp));
}

__global__ void convx_kernel(const float* x, uint16_t* xb) {
  int i = blockIdx.x * 256 + threadIdx.x;   // 4096 blocks, 4 floats each
  float4 v = ((const float4*)x)[i];
  ushort4 o = make_ushort4(f2bf(v.x), f2bf(v.y), f2bf(v.z), f2bf(v.w));
  ((ushort4*)xb)[i] = o;
}

// transpose+convert 7 weight matrices to B^T (N x K) bf16 layouts
__global__ void wtrans_kernel(const float* w0, const float* w1, const float* w2,
                              const float* w3, const float* w4, const float* w5,
                              const float* w6, uint16_t* wt, uint16_t* wtt, uint16_t* wot) {
  int z = blockIdx.y;
  const float* src; uint16_t* dst; int C;
  if (z < 3)      { src = (z==0)?w0:((z==1)?w1:w2); dst = wt  + (size_t)z*524288;     C=2048; }
  else if (z < 6) { src = (z==3)?w3:((z==4)?w4:w5); dst = wtt + (size_t)(z-3)*524288; C=2048; }
  else            { src = w6; dst = wot;                                              C=256; }
  int R = (z < 6) ? 256 : 2048;
  __shared__ uint16_t tile[32][33];
  int tc = C >> 5;
  int bR = (blockIdx.x / tc) << 5, bC = (blockIdx.x % tc) << 5;
  int tx = threadIdx.x & 31, ty = threadIdx.x >> 5;  // 32 x 8
  #pragma unroll
  for (int i = 0; i < 4; i++) {
    int r = bR + ty + i * 8;
    tile[ty + i * 8][tx] = f2bf(src[(size_t)r * C + bC + tx]);
  }
  __syncthreads();
  #pragma unroll
  for (int i = 0; i < 4; i++) {
    int c = bC + ty + i * 8;
    dst[(size_t)c * R + bR + tx] = tile[tx][ty + i * 8];
  }
}

// ---------------- bias GEMM (no LDS): [3] x (m[64x256] @ Wt[256x2048] + b) -> fp32 ----------------
__global__ __launch_bounds__(256, 4)
void bias_gemm(const uint16_t* Mb, const uint16_t* WTT,
               const float* bq, const float* bk, const float* bv, float* biasAll) {
  int bid = blockIdx.x;            // 48 = 3 * 16
  int z = bid >> 4, nbt = bid & 15;
  int n0 = nbt << 7;
  const uint16_t* Bsrc = WTT + (size_t)z * 524288;
  const float* bvec = (z == 0) ? bq : ((z == 1) ? bk : bv);
  float* outp = biasAll + (size_t)z * 131072;
  int tid = threadIdx.x, lane = tid & 63, w = tid >> 6;
  int g = lane >> 4, ln = lane & 15;

  bf16x8 af[8];
  #pragma unroll
  for (int ks = 0; ks < 8; ks++)
    af[ks] = ld16(Mb + (size_t)(w*16 + ln) * 256 + ks*32 + g*8);
  f32x4 acc[8];
  #pragma unroll
  for (int j = 0; j < 8; j++) acc[j] = (f32x4){0.f,0.f,0.f,0.f};
  #pragma unroll
  for (int j = 0; j < 8; j++)
    #pragma unroll
    for (int ks = 0; ks < 8; ks++) {
      bf16x8 bf_ = ld16(Bsrc + (size_t)(n0 + j*16 + ln) * 256 + ks*32 + g*8);
      acc[j] = MFMA16(af[ks], bf_, acc[j]);
    }
  #pragma unroll
  for (int j = 0; j < 8; j++) {
    int colg = n0 + j*16 + ln;
    float bb = bvec[colg];
    #pragma unroll
    for (int r = 0; r < 4; r++)
      outp[(size_t)(w*16 + g*4 + r) * 2048 + colg] = acc[j][r] + bb;
  }
}

// ---------------- KV GEMM v2: B-panel staged in LDS (attn_v4's proven pattern) ----------------
// grid 8192 = 2 * 256 * 16; block 256 = 4 waves; output tile 64 rows x 128 cols.
__global__ __launch_bounds__(256, 4)
void kv_gemm2(const uint16_t* Xb, const uint16_t* WT, const float* biasAll,
              uint16_t* Kw, uint16_t* Vt) {
  __shared__ char stage[32768];      // [64 rows][256 k] bf16, pitch 512B, 32 slots swz
  int bid = blockIdx.x;
  int z2 = bid >> 12, rem = bid & 4095;   // z2: 0=K, 1=V
  int mb = rem >> 4, nb = rem & 15;
  int m0 = mb << 6, n0 = nb << 7;     // 64-row x 128-col tile
  const uint16_t* Bsrc = WT + (size_t)(z2 + 1) * 524288;
  int bt = m0 >> 8;
  const float* bias = biasAll + (size_t)(z2 + 1) * 131072 + (size_t)bt * 2048;
  int tid = threadIdx.x, lane = tid & 63, w = tid >> 6;
  int g = lane >> 4, ln = lane & 15;

  // A fragments: each wave's 16 rows, read once, coalesced
  bf16x8 af[8];
  #pragma unroll
  for (int ks = 0; ks < 8; ks++)
    af[ks] = ld16(Xb + (size_t)(m0 + w*16 + ln) * 256 + ks*32 + g*8);
  f32x4 acc[8];
  #pragma unroll
  for (int j = 0; j < 8; j++) acc[j] = (f32x4){0.f,0.f,0.f,0.f};

  #pragma unroll
  for (int t = 0; t < 2; t++) {
    __syncthreads();
    // stage B rows [n0 + t*64, +64) x [256 k]  (256 threads x 8 iters x 16B)
    #pragma unroll
    for (int it = 0; it < 8; it++) {
      int c = tid + (it << 8);
      int row = c >> 5, sl = c & 31;
      u32x4 v = *(const u32x4*)(Bsrc + (size_t)(n0 + t*64 + row) * 256 + sl * 8);
      *(u32x4*)(stage + row * 512 + ((sl ^ (row & 7)) << 4)) = v;
    }
    __syncthreads();
    #pragma unroll
    for (int ks = 0; ks < 8; ks++)
      #pragma unroll
      for (int j2 = 0; j2 < 4; j2++) {
        int row = j2*16 + ln;
        u32x4 v = *(const u32x4*)(stage + row * 512 + ((((ks<<2)+g) ^ (row & 7)) << 4));
        acc[t*4+j2] = MFMA16(af[ks], __builtin_bit_cast(bf16x8, v), acc[t*4+j2]);
      }
  }

  // epilogue identical to v1: acc[j] -> colg = n0 + j*16 + ln
  #pragma unroll
  for (int j = 0; j < 8; j++) {
    int colg = n0 + j*16 + ln;
    int hh = colg >> 8, d = colg & 255;
    float bb = bias[colg];
    size_t hb = (size_t)(bt * 8 + hh) << 16;
    int l0 = (m0 & 255) + w*16 + g*4;
    if (z2 == 1) {   // V transposed: [d][l], 4 consecutive l per lane
      ushort4 pk = make_ushort4(f2bf(acc[j][0]+bb), f2bf(acc[j][1]+bb),
                                f2bf(acc[j][2]+bb), f2bf(acc[j][3]+bb));
      *(ushort4*)(Vt + hb + ((size_t)d << 8) + l0) = pk;
    } else {
      #pragma unroll
      for (int r = 0; r < 4; r++)
        Kw[hb + ((size_t)(l0 + r) << 8) + d] = f2bf(acc[j][r] + bb);
    }
  }
}

// ---------------- fused attention v4: shared LDS staging + per-wave bounce slabs ----------------
// block = (bt, h, qh); 1024 blocks; 8 waves x 16 q-rows.
// LDS: [0,32KB) shared stage buffer [64 rows][256 bf16] swz (sync-guarded);
//      [32KB,64KB) 8 x 4KB per-wave bounce slabs (wave-private).
__global__ __launch_bounds__(512, 2)
void attn_v4(const uint16_t* Xb, const uint16_t* WT, const float* Bi,
             const uint16_t* Kw, const uint16_t* Vt, const uint16_t* WoT,
             float* out) {
  __shared__ char smem[65536];
  int tid = threadIdx.x, lane = tid & 63, w = tid >> 6;
  int g = lane >> 4, ln = lane & 15;
  int bid = blockIdx.x;
  int bh = bid >> 1, qh = bid & 1;
  int bt = bh >> 3, h = bh & 7;
  const size_t kvbase = (size_t)bh << 16;
  int q0g = bt * 256 + qh * 128 + w * 16;   // first global q-row of this wave
  char* stage = smem;                        // shared [64][256]bf16, pitch 512B, 32 slots
  char* slab  = smem + 32768 + (w << 12);    // private 4KB

  // stage one [64 rows][256 cols] bf16 tile; rowstride in elements
  auto stage_tile = [&](const uint16_t* src, int rowstride) {
    #pragma unroll
    for (int it = 0; it < 4; it++) {
      int c = tid + (it << 9);
      int row = c >> 5, sl = c & 31;
      u32x4 v = *(const u32x4*)(src + (size_t)row * rowstride + sl * 8);
      *(u32x4*)(stage + row * 512 + ((sl ^ (row & 7)) << 4)) = v;
    }
  };
  auto frag = [&](int row, int slot) -> bf16x8 {
    u32x4 v = *(const u32x4*)(stage + row * 512 + ((slot ^ (row & 7)) << 4));
    return __builtin_bit_cast(bf16x8, v);
  };

  // ---- p0: Q = (X @ Wq[:,h] + bias_q) * (1/16); WqT tiles staged in LDS ----
  bf16x8 qx[8];
  #pragma unroll
  for (int ks = 0; ks < 8; ks++)
    qx[ks] = ld16(Xb + (size_t)(q0g + ln) * 256 + ks*32 + g*8);
  f32x4 qacc[16];
  #pragma unroll
  for (int f = 0; f < 16; f++) qacc[f] = (f32x4){0.f,0.f,0.f,0.f};
  #pragma unroll
  for (int t = 0; t < 4; t++) {
    __syncthreads();
    stage_tile(WT + (size_t)(h*256 + t*64) * 256, 256);
    __syncthreads();
    #pragma unroll
    for (int ks = 0; ks < 8; ks++)
      #pragma unroll
      for (int f2 = 0; f2 < 4; f2++)
        qacc[t*4+f2] = MFMA16(qx[ks], frag(f2*16 + ln, ks*4 + g), qacc[t*4+f2]);
  }
  #pragma unroll
  for (int f = 0; f < 16; f++) {
    float bb = Bi[bt*2048 + h*256 + f*16 + ln];
    #pragma unroll
    for (int r = 0; r < 4; r++) qacc[f][r] = (qacc[f][r] + bb) * 0.0625f;
  }
  // Q bounce (per-wave slab)
  bf16x8 qa[8];
  #pragma unroll
  for (int dh = 0; dh < 2; dh++) {
    #pragma unroll
    for (int f2 = 0; f2 < 8; f2++) {
      int f = dh*8 + f2;
      #pragma unroll
      for (int r = 0; r < 4; r++)
        bounce_w2(slab, g*4 + r, f2*16 + ln, f2bf(qacc[f][r]));
    }
    #pragma unroll
    for (int ks2 = 0; ks2 < 4; ks2++)
      qa[dh*4 + ks2] = bounce_r16(slab, ln, ks2*4 + g);
  }

  // ---- p1: S = Q K^T; K tiles staged in LDS ----
  f32x4 S[16];
  #pragma unroll
  for (int f = 0; f < 16; f++) S[f] = (f32x4){0.f,0.f,0.f,0.f};
  #pragma unroll
  for (int t = 0; t < 4; t++) {
    __syncthreads();
    stage_tile(Kw + kvbase + (size_t)(t*64) * 256, 256);
    __syncthreads();
    #pragma unroll
    for (int ks = 0; ks < 8; ks++)
      #pragma unroll
      for (int f2 = 0; f2 < 4; f2++)
        S[t*4+f2] = MFMA16(qa[ks], frag(f2*16 + ln, ks*4 + g), S[t*4+f2]);
  }

  // ---- p2: row softmax ----
  #pragma unroll
  for (int r = 0; r < 4; r++) {
    float mx = -3.4e38f;
    #pragma unroll
    for (int f = 0; f < 16; f++) mx = fmaxf(mx, S[f][r]);
    #pragma unroll
    for (int m_ = 1; m_ < 16; m_ <<= 1) mx = fmaxf(mx, __shfl_xor(mx, m_, 64));
    float sum = 0.f;
    #pragma unroll
    for (int f = 0; f < 16; f++) {
      float p = __expf(S[f][r] - mx);
      S[f][r] = p; sum += p;
    }
    #pragma unroll
    for (int m_ = 1; m_ < 16; m_ <<= 1) sum += __shfl_xor(sum, m_, 64);
    float inv = 1.f / sum;
    #pragma unroll
    for (int f = 0; f < 16; f++) S[f][r] *= inv;
  }

  // ---- p3: P bounce (per-wave slab); O^T = V^T P^T with V^T tiles staged ----
  bf16x8 pb[8];
  #pragma unroll
  for (int kh = 0; kh < 2; kh++) {
    #pragma unroll
    for (int f2 = 0; f2 < 8; f2++) {
      int f = kh*8 + f2;
      #pragma unroll
      for (int r = 0; r < 4; r++)
        bounce_w2(slab, g*4 + r, f2*16 + ln, f2bf(S[f][r]));
    }
    #pragma unroll
    for (int ks2 = 0; ks2 < 4; ks2++)
      pb[kh*4 + ks2] = bounce_r16(slab, ln, ks2*4 + g);
  }

  f32x4 O[16];
  #pragma unroll
  for (int df = 0; df < 16; df++) O[df] = (f32x4){0.f,0.f,0.f,0.f};
  #pragma unroll
  for (int t = 0; t < 4; t++) {
    __syncthreads();
    stage_tile(Vt + kvbase + (size_t)(t*64) * 256, 256);
    __syncthreads();
    #pragma unroll
    for (int ks = 0; ks < 8; ks++)
      #pragma unroll
      for (int df2 = 0; df2 < 4; df2++)
        O[t*4+df2] = MFMA16(frag(df2*16 + ln, ks*4 + g), pb[ks], O[t*4+df2]);  // D[m=d][n=q]
  }

  // ---- p4: O bounce (per-wave slab) ----
  bf16x8 oa[8];
  #pragma unroll
  for (int dh = 0; dh < 2; dh++) {
    #pragma unroll
    for (int df2 = 0; df2 < 8; df2++) {
      int df = dh*8 + df2;
      #pragma unroll
      for (int r = 0; r < 4; r++)
        bounce_w2(slab, ln, df2*16 + g*4 + r, f2bf(O[df][r]));
    }
    #pragma unroll
    for (int ks2 = 0; ks2 < 4; ks2++)
      oa[dh*4 + ks2] = bounce_r16(slab, ln, ks2*4 + g);
  }

  // ---- p5: out += O @ Wo[h*256:(h+1)*256]; WoT tiles staged in LDS ----
  f32x4 oacc[16];
  #pragma unroll
  for (int ef = 0; ef < 16; ef++) oacc[ef] = (f32x4){0.f,0.f,0.f,0.f};
  #pragma unroll
  for (int t = 0; t < 4; t++) {
    __syncthreads();
    stage_tile(WoT + (size_t)(t*64) * 2048 + h*256, 2048);
    __syncthreads();
    #pragma unroll
    for (int ks = 0; ks < 8; ks++)
      #pragma unroll
      for (int ef2 = 0; ef2 < 4; ef2++)
        oacc[t*4+ef2] = MFMA16(oa[ks], frag(ef2*16 + ln, ks*4 + g), oacc[t*4+ef2]);
  }
  #pragma unroll
  for (int ef = 0; ef < 16; ef++)
    #pragma unroll
    for (int r = 0; r < 4; r++)
      atomicAdd(out + (size_t)(q0g + g*4 + r) * 256 + ef*16 + ln, oacc[ef][r]);
}

// ---------------- launcher ----------------
extern "C" void kernel_launch(void* const* d_in, const int* in_sizes, int n_in,
                              void* d_out, int out_size, void* d_ws, size_t ws_size,
                              hipStream_t stream) {
  float* out = (float*)d_out;
  if (ws_size < WS_NEED) {
    sentinel_kernel<<<16384, 256, 0, stream>>>(out, 1000.0f + (float)(ws_size >> 20));
    return;
  }
  const float* x   = (const float*)d_in[0];
  const float* te  = (const float*)d_in[1];
  const float* re  = (const float*)d_in[2];
  const float* Wq  = (const float*)d_in[3];
  const float* Wk  = (const float*)d_in[4];
  const float* Wv  = (const float*)d_in[5];
  const float* Wqt = (const float*)d_in[6];
  const float* bqt = (const float*)d_in[7];
  const float* Wkt = (const float*)d_in[8];
  const float* bkt = (const float*)d_in[9];
  const float* Wvt = (const float*)d_in[10];
  const float* bvt = (const float*)d_in[11];
  const float* Wo  = (const float*)d_in[12];
  const float* bo  = (const float*)d_in[13];
  char* ws = (char*)d_ws;
  uint16_t* Xb  = (uint16_t*)(ws + OFF_XB);
  uint16_t* WT  = (uint16_t*)(ws + OFF_WT);
  uint16_t* WTT = (uint16_t*)(ws + OFF_WTT);
  uint16_t* WoT = (uint16_t*)(ws + OFF_WOT);
  uint16_t* Mb  = (uint16_t*)(ws + OFF_MB);
  float*    Bi  = (float*)(ws + OFF_BIAS);
  uint16_t* Kw  = (uint16_t*)(ws + OFF_K);
  uint16_t* Vt  = (uint16_t*)(ws + OFF_VT);

  mish_kernel<<<64, 256, 0, stream>>>(te, re, Mb);
  wtrans_kernel<<<dim3(512, 7), 256, 0, stream>>>(Wq, Wk, Wv, Wqt, Wkt, Wvt, Wo, WT, WTT, WoT);
  convx_kernel<<<4096, 256, 0, stream>>>(x, Xb);
  bias_gemm<<<48, 256, 0, stream>>>(Mb, WTT, bqt, bkt, bvt, Bi);
  kv_gemm2<<<8192, 256, 0, stream>>>(Xb, WT, Bi, Kw, Vt);
  init_out<<<16384, 256, 0, stream>>>(bo, out);
  attn_v4<<<1024, 512, 0, stream>>>(Xb, WT, Bi, Kw, Vt, WoT, out);
}

// Round 8
// 299.373 us; speedup vs baseline: 2.8530x; 1.0831x over previous
//
#include <hip/hip_runtime.h>
#include <stdint.h>

typedef __bf16 bf16x8 __attribute__((ext_vector_type(8)));
typedef float f32x4 __attribute__((ext_vector_type(4)));
typedef uint32_t u32x4 __attribute__((ext_vector_type(4)));

#define MFMA16(a,b,c) __builtin_amdgcn_mfma_f32_16x16x32_bf16(a,b,c,0,0,0)

// ---------------- workspace layout (bytes), total 151,552,000 ----------------
#define OFF_XB   0ull           // X bf16 [16384][256]              8,388,608
#define OFF_WT   8388608ull     // WqT/WkT/WvT bf16 [3][2048][256]  3,145,728
#define OFF_WTT  11534336ull    // Wq_tT/Wk_tT/Wv_tT same           3,145,728
#define OFF_WOT  14680064ull    // WoT bf16 [256][2048]             1,048,576
#define OFF_MB   15728640ull    // mish(t+r) bf16 [64][256]            32,768
#define OFF_BIAS 15761408ull    // bias fp32 [3][64][2048]          1,572,864
#define OFF_K    17334272ull    // K bf16 [512][256 l][256 d]      67,108,864
#define OFF_VT   84443136ull    // V^T bf16 [512][256 d][256 l]    67,108,864
#define WS_NEED  151552000ull

__device__ __forceinline__ uint16_t f2bf(float f) {
  uint32_t u = __builtin_bit_cast(uint32_t, f);
  return (uint16_t)((u + 0x7fffu + ((u >> 16) & 1u)) >> 16);
}
__device__ __forceinline__ bf16x8 ld16(const uint16_t* p) {
  u32x4 v = *(const u32x4*)p;
  return __builtin_bit_cast(bf16x8, v);
}
// per-wave 4KB bounce slab: [16 rows][128 bf16], row pitch 256B = 16 x 16B slots,
// slot XOR-swizzled by row&7.
__device__ __forceinline__ void bounce_w2(char* slab, int row, int col, uint16_t val) {
  int slot = col >> 3;
  *(uint16_t*)(slab + row * 256 + (((slot ^ (row & 7)) & 15) << 4) + ((col & 7) << 1)) = val;
}
__device__ __forceinline__ bf16x8 bounce_r16(const char* slab, int row, int slot) {
  u32x4 v = *(const u32x4*)(slab + row * 256 + (((slot ^ (row & 7)) & 15) << 4));
  return __builtin_bit_cast(bf16x8, v);
}

// ---------------- ws-size sentinel + output init ----------------
__global__ void sentinel_kernel(float* out, float val) {
  out[blockIdx.x * 256 + threadIdx.x] = val;
}
__global__ void init_out(const float* bo, float* out) {
  int i = blockIdx.x * 256 + threadIdx.x;
  out[i] = bo[i & 255];
}

// ---------------- small prep kernels ----------------
__global__ void mish_kernel(const float* te, const float* re, uint16_t* mb) {
  int i = blockIdx.x * 256 + threadIdx.x;   // 64*256
  float x = te[i] + re[i];
  float sp = log1pf(__expf(x));
  mb[i] = f2bf(x * tanhf(sp));
}

__global__ void convx_kernel(const float* x, uint16_t* xb) {
  int i = blockIdx.x * 256 + threadIdx.x;   // 4096 blocks, 4 floats each
  float4 v = ((const float4*)x)[i];
  ushort4 o = make_ushort4(f2bf(v.x), f2bf(v.y), f2bf(v.z), f2bf(v.w));
  ((ushort4*)xb)[i] = o;
}

// transpose+convert 7 weight matrices to B^T (N x K) bf16 layouts
__global__ void wtrans_kernel(const float* w0, const float* w1, const float* w2,
                              const float* w3, const float* w4, const float* w5,
                              const float* w6, uint16_t* wt, uint16_t* wtt, uint16_t* wot) {
  int z = blockIdx.y;
  const float* src; uint16_t* dst; int C;
  if (z < 3)      { src = (z==0)?w0:((z==1)?w1:w2); dst = wt  + (size_t)z*524288;     C=2048; }
  else if (z < 6) { src = (z==3)?w3:((z==4)?w4:w5); dst = wtt + (size_t)(z-3)*524288; C=2048; }
  else            { src = w6; dst = wot;                                              C=256; }
  int R = (z < 6) ? 256 : 2048;
  __shared__ uint16_t tile[32][33];
  int tc = C >> 5;
  int bR = (blockIdx.x / tc) << 5, bC = (blockIdx.x % tc) << 5;
  int tx = threadIdx.x & 31, ty = threadIdx.x >> 5;  // 32 x 8
  #pragma unroll
  for (int i = 0; i < 4; i++) {
    int r = bR + ty + i * 8;
    tile[ty + i * 8][tx] = f2bf(src[(size_t)r * C + bC + tx]);
  }
  __syncthreads();
  #pragma unroll
  for (int i = 0; i < 4; i++) {
    int c = bC + ty + i * 8;
    dst[(size_t)c * R + bR + tx] = tile[tx][ty + i * 8];
  }
}

// ---------------- bias GEMM (no LDS): [3] x (m[64x256] @ Wt[256x2048] + b) -> fp32 ----------------
__global__ __launch_bounds__(256, 4)
void bias_gemm(const uint16_t* Mb, const uint16_t* WTT,
               const float* bq, const float* bk, const float* bv, float* biasAll) {
  int bid = blockIdx.x;            // 48 = 3 * 16
  int z = bid >> 4, nbt = bid & 15;
  int n0 = nbt << 7;
  const uint16_t* Bsrc = WTT + (size_t)z * 524288;
  const float* bvec = (z == 0) ? bq : ((z == 1) ? bk : bv);
  float* outp = biasAll + (size_t)z * 131072;
  int tid = threadIdx.x, lane = tid & 63, w = tid >> 6;
  int g = lane >> 4, ln = lane & 15;

  bf16x8 af[8];
  #pragma unroll
  for (int ks = 0; ks < 8; ks++)
    af[ks] = ld16(Mb + (size_t)(w*16 + ln) * 256 + ks*32 + g*8);
  f32x4 acc[8];
  #pragma unroll
  for (int j = 0; j < 8; j++) acc[j] = (f32x4){0.f,0.f,0.f,0.f};
  #pragma unroll
  for (int j = 0; j < 8; j++)
    #pragma unroll
    for (int ks = 0; ks < 8; ks++) {
      bf16x8 bf_ = ld16(Bsrc + (size_t)(n0 + j*16 + ln) * 256 + ks*32 + g*8);
      acc[j] = MFMA16(af[ks], bf_, acc[j]);
    }
  #pragma unroll
  for (int j = 0; j < 8; j++) {
    int colg = n0 + j*16 + ln;
    float bb = bvec[colg];
    #pragma unroll
    for (int r = 0; r < 4; r++)
      outp[(size_t)(w*16 + g*4 + r) * 2048 + colg] = acc[j][r] + bb;
  }
}

// ---------------- KV GEMM v3: B-panel staged in LDS + async issue/commit split ----------------
// grid 8192 = 2 * 256 * 16; block 256 = 4 waves; output tile 64 rows x 128 cols.
__global__ __launch_bounds__(256, 4)
void kv_gemm3(const uint16_t* Xb, const uint16_t* WT, const float* biasAll,
              uint16_t* Kw, uint16_t* Vt) {
  __shared__ char stage[32768];      // [64 rows][256 k] bf16, pitch 512B, 32 slots swz
  int bid = blockIdx.x;
  int z2 = bid >> 12, rem = bid & 4095;   // z2: 0=K, 1=V
  int mb = rem >> 4, nb = rem & 15;
  int m0 = mb << 6, n0 = nb << 7;     // 64-row x 128-col tile
  const uint16_t* Bsrc = WT + (size_t)(z2 + 1) * 524288;
  int bt = m0 >> 8;
  const float* bias = biasAll + (size_t)(z2 + 1) * 131072 + (size_t)bt * 2048;
  int tid = threadIdx.x, lane = tid & 63, w = tid >> 6;
  int g = lane >> 4, ln = lane & 15;

  u32x4 rb[8];
  auto issueB = [&](int t) {
    #pragma unroll
    for (int it = 0; it < 8; it++) {
      int c = tid + (it << 8);
      int row = c >> 5, sl = c & 31;
      rb[it] = *(const u32x4*)(Bsrc + (size_t)(n0 + t*64 + row) * 256 + sl * 8);
    }
  };
  issueB(0);                          // tile-0 loads in flight
  // A fragments: each wave's 16 rows, read once, coalesced (overlaps with tile-0)
  bf16x8 af[8];
  #pragma unroll
  for (int ks = 0; ks < 8; ks++)
    af[ks] = ld16(Xb + (size_t)(m0 + w*16 + ln) * 256 + ks*32 + g*8);
  f32x4 acc[8];
  #pragma unroll
  for (int j = 0; j < 8; j++) acc[j] = (f32x4){0.f,0.f,0.f,0.f};

  #pragma unroll
  for (int t = 0; t < 2; t++) {
    __syncthreads();
    #pragma unroll
    for (int it = 0; it < 8; it++) {   // commit regs -> LDS
      int c = tid + (it << 8);
      int row = c >> 5, sl = c & 31;
      *(u32x4*)(stage + row * 512 + ((sl ^ (row & 7)) << 4)) = rb[it];
    }
    __syncthreads();
    if (t == 0) issueB(1);             // next-tile loads fly under the MFMAs
    #pragma unroll
    for (int ks = 0; ks < 8; ks++)
      #pragma unroll
      for (int j2 = 0; j2 < 4; j2++) {
        int row = j2*16 + ln;
        u32x4 v = *(const u32x4*)(stage + row * 512 + ((((ks<<2)+g) ^ (row & 7)) << 4));
        acc[t*4+j2] = MFMA16(af[ks], __builtin_bit_cast(bf16x8, v), acc[t*4+j2]);
      }
  }

  // epilogue: acc[j] -> colg = n0 + j*16 + ln
  #pragma unroll
  for (int j = 0; j < 8; j++) {
    int colg = n0 + j*16 + ln;
    int hh = colg >> 8, d = colg & 255;
    float bb = bias[colg];
    size_t hb = (size_t)(bt * 8 + hh) << 16;
    int l0 = (m0 & 255) + w*16 + g*4;
    if (z2 == 1) {   // V transposed: [d][l], 4 consecutive l per lane
      ushort4 pk = make_ushort4(f2bf(acc[j][0]+bb), f2bf(acc[j][1]+bb),
                                f2bf(acc[j][2]+bb), f2bf(acc[j][3]+bb));
      *(ushort4*)(Vt + hb + ((size_t)d << 8) + l0) = pk;
    } else {
      #pragma unroll
      for (int r = 0; r < 4; r++)
        Kw[hb + ((size_t)(l0 + r) << 8) + d] = f2bf(acc[j][r] + bb);
    }
  }
}

// ---------------- fused attention v5: v4 + async issue/commit staging split ----------------
// block = (bt, h, qh); 1024 blocks; 8 waves x 16 q-rows.
// LDS: [0,32KB) shared stage (sync-guarded); [32KB,64KB) per-wave bounce slabs (private).
// Tile t+1's global loads are issued before tile t's MFMA consume; each phase's tile-0
// loads are issued before the preceding bounce/softmax work.
__global__ __launch_bounds__(512, 4)
void attn_v5(const uint16_t* Xb, const uint16_t* WT, const float* Bi,
             const uint16_t* Kw, const uint16_t* Vt, const uint16_t* WoT,
             float* out) {
  __shared__ char smem[65536];
  int tid = threadIdx.x, lane = tid & 63, w = tid >> 6;
  int g = lane >> 4, ln = lane & 15;
  int bid = blockIdx.x;
  int bh = bid >> 1, qh = bid & 1;
  int bt = bh >> 3, h = bh & 7;
  const size_t kvbase = (size_t)bh << 16;
  int q0g = bt * 256 + qh * 128 + w * 16;   // first global q-row of this wave
  char* stage = smem;                        // shared [64][256]bf16, pitch 512B, 32 slots
  char* slab  = smem + 32768 + (w << 12);    // private 4KB

  u32x4 rv[4];
  auto issue_tile = [&](const uint16_t* src, int rowstride) {
    #pragma unroll
    for (int it = 0; it < 4; it++) {
      int c = tid + (it << 9);
      int row = c >> 5, sl = c & 31;
      rv[it] = *(const u32x4*)(src + (size_t)row * rowstride + sl * 8);
    }
  };
  auto commit_tile = [&]() {
    #pragma unroll
    for (int it = 0; it < 4; it++) {
      int c = tid + (it << 9);
      int row = c >> 5, sl = c & 31;
      *(u32x4*)(stage + row * 512 + ((sl ^ (row & 7)) << 4)) = rv[it];
    }
  };
  auto frag = [&](int row, int slot) -> bf16x8 {
    u32x4 v = *(const u32x4*)(stage + row * 512 + ((slot ^ (row & 7)) << 4));
    return __builtin_bit_cast(bf16x8, v);
  };

  // ---- p0: Q = (X @ Wq[:,h] + bias_q) * (1/16); WqT tiles staged, pipelined ----
  issue_tile(WT + (size_t)(h*256) * 256, 256);          // WqT tile 0
  bf16x8 qx[8];
  #pragma unroll
  for (int ks = 0; ks < 8; ks++)
    qx[ks] = ld16(Xb + (size_t)(q0g + ln) * 256 + ks*32 + g*8);
  f32x4 qacc[16];
  #pragma unroll
  for (int f = 0; f < 16; f++) qacc[f] = (f32x4){0.f,0.f,0.f,0.f};
  #pragma unroll
  for (int t = 0; t < 4; t++) {
    __syncthreads();
    commit_tile();
    __syncthreads();
    if (t < 3) issue_tile(WT + (size_t)(h*256 + (t+1)*64) * 256, 256);
    #pragma unroll
    for (int ks = 0; ks < 8; ks++)
      #pragma unroll
      for (int f2 = 0; f2 < 4; f2++)
        qacc[t*4+f2] = MFMA16(qx[ks], frag(f2*16 + ln, ks*4 + g), qacc[t*4+f2]);
  }
  issue_tile(Kw + kvbase, 256);                          // K tile 0 flies under bounce
  #pragma unroll
  for (int f = 0; f < 16; f++) {
    float bb = Bi[bt*2048 + h*256 + f*16 + ln];
    #pragma unroll
    for (int r = 0; r < 4; r++) qacc[f][r] = (qacc[f][r] + bb) * 0.0625f;
  }
  // Q bounce (per-wave slab, no barrier needed)
  bf16x8 qa[8];
  #pragma unroll
  for (int dh = 0; dh < 2; dh++) {
    #pragma unroll
    for (int f2 = 0; f2 < 8; f2++) {
      int f = dh*8 + f2;
      #pragma unroll
      for (int r = 0; r < 4; r++)
        bounce_w2(slab, g*4 + r, f2*16 + ln, f2bf(qacc[f][r]));
    }
    #pragma unroll
    for (int ks2 = 0; ks2 < 4; ks2++)
      qa[dh*4 + ks2] = bounce_r16(slab, ln, ks2*4 + g);
  }

  // ---- p1: S = Q K^T; K tiles staged, pipelined ----
  f32x4 S[16];
  #pragma unroll
  for (int f = 0; f < 16; f++) S[f] = (f32x4){0.f,0.f,0.f,0.f};
  #pragma unroll
  for (int t = 0; t < 4; t++) {
    __syncthreads();
    commit_tile();
    __syncthreads();
    if (t < 3) issue_tile(Kw + kvbase + (size_t)((t+1)*64) * 256, 256);
    #pragma unroll
    for (int ks = 0; ks < 8; ks++)
      #pragma unroll
      for (int f2 = 0; f2 < 4; f2++)
        S[t*4+f2] = MFMA16(qa[ks], frag(f2*16 + ln, ks*4 + g), S[t*4+f2]);
  }
  issue_tile(Vt + kvbase, 256);                          // V tile 0 flies under softmax

  // ---- p2: row softmax ----
  #pragma unroll
  for (int r = 0; r < 4; r++) {
    float mx = -3.4e38f;
    #pragma unroll
    for (int f = 0; f < 16; f++) mx = fmaxf(mx, S[f][r]);
    #pragma unroll
    for (int m_ = 1; m_ < 16; m_ <<= 1) mx = fmaxf(mx, __shfl_xor(mx, m_, 64));
    float sum = 0.f;
    #pragma unroll
    for (int f = 0; f < 16; f++) {
      float p = __expf(S[f][r] - mx);
      S[f][r] = p; sum += p;
    }
    #pragma unroll
    for (int m_ = 1; m_ < 16; m_ <<= 1) sum += __shfl_xor(sum, m_, 64);
    float inv = 1.f / sum;
    #pragma unroll
    for (int f = 0; f < 16; f++) S[f][r] *= inv;
  }

  // ---- p3: P bounce (per-wave slab); O^T = V^T P^T, V^T tiles staged, pipelined ----
  bf16x8 pb[8];
  #pragma unroll
  for (int kh = 0; kh < 2; kh++) {
    #pragma unroll
    for (int f2 = 0; f2 < 8; f2++) {
      int f = kh*8 + f2;
      #pragma unroll
      for (int r = 0; r < 4; r++)
        bounce_w2(slab, g*4 + r, f2*16 + ln, f2bf(S[f][r]));
    }
    #pragma unroll
    for (int ks2 = 0; ks2 < 4; ks2++)
      pb[kh*4 + ks2] = bounce_r16(slab, ln, ks2*4 + g);
  }

  f32x4 O[16];
  #pragma unroll
  for (int df = 0; df < 16; df++) O[df] = (f32x4){0.f,0.f,0.f,0.f};
  #pragma unroll
  for (int t = 0; t < 4; t++) {
    __syncthreads();
    commit_tile();
    __syncthreads();
    if (t < 3) issue_tile(Vt + kvbase + (size_t)((t+1)*64) * 256, 256);
    #pragma unroll
    for (int ks = 0; ks < 8; ks++)
      #pragma unroll
      for (int df2 = 0; df2 < 4; df2++)
        O[t*4+df2] = MFMA16(frag(df2*16 + ln, ks*4 + g), pb[ks], O[t*4+df2]);  // D[m=d][n=q]
  }
  issue_tile(WoT + (size_t)0 * 2048 + h*256, 2048);      // WoT tile 0 flies under bounce

  // ---- p4: O bounce (per-wave slab) ----
  bf16x8 oa[8];
  #pragma unroll
  for (int dh = 0; dh < 2; dh++) {
    #pragma unroll
    for (int df2 = 0; df2 < 8; df2++) {
      int df = dh*8 + df2;
      #pragma unroll
      for (int r = 0; r < 4; r++)
        bounce_w2(slab, ln, df2*16 + g*4 + r, f2bf(O[df][r]));
    }
    #pragma unroll
    for (int ks2 = 0; ks2 < 4; ks2++)
      oa[dh*4 + ks2] = bounce_r16(slab, ln, ks2*4 + g);
  }

  // ---- p5: out += O @ Wo[h*256:(h+1)*256]; WoT tiles staged, pipelined ----
  f32x4 oacc[16];
  #pragma unroll
  for (int ef = 0; ef < 16; ef++) oacc[ef] = (f32x4){0.f,0.f,0.f,0.f};
  #pragma unroll
  for (int t = 0; t < 4; t++) {
    __syncthreads();
    commit_tile();
    __syncthreads();
    if (t < 3) issue_tile(WoT + (size_t)((t+1)*64) * 2048 + h*256, 2048);
    #pragma unroll
    for (int ks = 0; ks < 8; ks++)
      #pragma unroll
      for (int ef2 = 0; ef2 < 4; ef2++)
        oacc[t*4+ef2] = MFMA16(oa[ks], frag(ef2*16 + ln, ks*4 + g), oacc[t*4+ef2]);
  }
  #pragma unroll
  for (int ef = 0; ef < 16; ef++)
    #pragma unroll
    for (int r = 0; r < 4; r++)
      atomicAdd(out + (size_t)(q0g + g*4 + r) * 256 + ef*16 + ln, oacc[ef][r]);
}

// ---------------- launcher ----------------
extern "C" void kernel_launch(void* const* d_in, const int* in_sizes, int n_in,
                              void* d_out, int out_size, void* d_ws, size_t ws_size,
                              hipStream_t stream) {
  float* out = (float*)d_out;
  if (ws_size < WS_NEED) {
    sentinel_kernel<<<16384, 256, 0, stream>>>(out, 1000.0f + (float)(ws_size >> 20));
    return;
  }
  const float* x   = (const float*)d_in[0];
  const float* te  = (const float*)d_in[1];
  const float* re  = (const float*)d_in[2];
  const float* Wq  = (const float*)d_in[3];
  const float* Wk  = (const float*)d_in[4];
  const float* Wv  = (const float*)d_in[5];
  const float* Wqt = (const float*)d_in[6];
  const float* bqt = (const float*)d_in[7];
  const float* Wkt = (const float*)d_in[8];
  const float* bkt = (const float*)d_in[9];
  const float* Wvt = (const float*)d_in[10];
  const float* bvt = (const float*)d_in[11];
  const float* Wo  = (const float*)d_in[12];
  const float* bo  = (const float*)d_in[13];
  char* ws = (char*)d_ws;
  uint16_t* Xb  = (uint16_t*)(ws + OFF_XB);
  uint16_t* WT  = (uint16_t*)(ws + OFF_WT);
  uint16_t* WTT = (uint16_t*)(ws + OFF_WTT);
  uint16_t* WoT = (uint16_t*)(ws + OFF_WOT);
  uint16_t* Mb  = (uint16_t*)(ws + OFF_MB);
  float*    Bi  = (float*)(ws + OFF_BIAS);
  uint16_t* Kw  = (uint16_t*)(ws + OFF_K);
  uint16_t* Vt  = (uint16_t*)(ws + OFF_VT);

  mish_kernel<<<64, 256, 0, stream>>>(te, re, Mb);
  wtrans_kernel<<<dim3(512, 7), 256, 0, stream>>>(Wq, Wk, Wv, Wqt, Wkt, Wvt, Wo, WT, WTT, WoT);
  convx_kernel<<<4096, 256, 0, stream>>>(x, Xb);
  bias_gemm<<<48, 256, 0, stream>>>(Mb, WTT, bqt, bkt, bvt, Bi);
  kv_gemm3<<<8192, 256, 0, stream>>>(Xb, WT, Bi, Kw, Vt);
  init_out<<<16384, 256, 0, stream>>>(bo, out);
  attn_v5<<<1024, 512, 0, stream>>>(Xb, WT, Bi, Kw, Vt, WoT, out);
}